// Round 4
// baseline (642.008 us; speedup 1.0000x reference)
//
#include <hip/hip_runtime.h>
#include <hip/hip_bf16.h>

typedef unsigned short u16;
typedef __attribute__((ext_vector_type(4))) unsigned short u16x4;
typedef __attribute__((ext_vector_type(8))) unsigned short u16x8;
typedef __attribute__((ext_vector_type(8))) short s16x8;
typedef __attribute__((ext_vector_type(4))) float f32x4;

#define HEADS 12
#define NSEQ 1024
#define DIMM 768
#define DHEAD 64

__device__ __forceinline__ float b2f(u16 h) {
  union { unsigned u; float f; } v; v.u = ((unsigned)h) << 16; return v.f;
}
__device__ __forceinline__ u16 f2b(float f) {
  union { float f; unsigned u; } v; v.f = f;
  unsigned r = v.u + 0x7fffu + ((v.u >> 16) & 1u);
  return (u16)(r >> 16);
}
__device__ __forceinline__ float ld(const void* p, long i, bool f32m) {
  return f32m ? ((const float*)p)[i] : b2f(((const u16*)p)[i]);
}

// probe lnq_g (all ones): f32 word = 0x3F800000, bf16-pair word = 0x3F803F80
__global__ void detect_dtype(const unsigned* __restrict__ probe, int* __restrict__ flag)
{
  if (threadIdx.x == 0) { flag[0] = (probe[0] == 0x3F800000u) ? 1 : 0; flag[1] = 0; }
}

// ---------------------------------------------------------------- GEMM (BT)
// C[m][n] = alpha * sum_k A[m][k] * BT[n][k] (+bias) (GELU) (+resid); C bf16.
template<int BM, int BN, bool GELU, bool RESID>
__global__ __launch_bounds__(256)
void gemm_bt(const u16* __restrict__ A, const u16* __restrict__ BT,
             const void* __restrict__ bias, const u16* __restrict__ resid,
             u16* __restrict__ C, const int* __restrict__ fl,
             int K, int lda, int ldb, int ldc,
             long sAo, long sAi, long sBo, long sBi, long sCo, long sCi,
             float alpha)
{
  constexpr int BK = 32;
  constexpr int PAD = 8;   // row stride 80 B: 16B-aligned, benign 2-way LDS aliasing
  constexpr int WM = BM / 2, WN = BN / 2;
  constexpr int MI = WM / 16, NI = WN / 16;
  __shared__ u16 As[BM][BK + PAD];
  __shared__ u16 Bs[BN][BK + PAD];

  const int z = blockIdx.z;
  const int zo = z / HEADS, zi = z - zo * HEADS;
  const u16* Ab = A + zo * sAo + zi * sAi;
  const u16* Bb = BT + zo * sBo + zi * sBi;
  u16* Cb = C + zo * sCo + zi * sCi;

  const int m0 = blockIdx.x * BM;
  const int n0 = blockIdx.y * BN;
  const int tid = threadIdx.x;
  const int lane = tid & 63;
  const int wv = tid >> 6;
  const int wm0 = (wv >> 1) * WM;
  const int wn0 = (wv & 1) * WN;
  const int l15 = lane & 15;
  const int quad = lane >> 4;

  f32x4 acc[MI][NI];
  #pragma unroll
  for (int i = 0; i < MI; ++i)
    #pragma unroll
    for (int j = 0; j < NI; ++j)
      acc[i][j] = {0.f, 0.f, 0.f, 0.f};

  const int r = tid >> 2;
  const int c8 = (tid & 3) * 8;

  for (int k0 = 0; k0 < K; k0 += BK) {
    __syncthreads();
    #pragma unroll
    for (int rr = 0; rr < BM; rr += 64)
      *(u16x8*)&As[r + rr][c8] = *(const u16x8*)&Ab[(long)(m0 + r + rr) * lda + k0 + c8];
    #pragma unroll
    for (int rr = 0; rr < BN; rr += 64)
      *(u16x8*)&Bs[r + rr][c8] = *(const u16x8*)&Bb[(long)(n0 + r + rr) * ldb + k0 + c8];
    __syncthreads();

    s16x8 af[MI], bfr[NI];
    #pragma unroll
    for (int i = 0; i < MI; ++i)
      af[i] = *(const s16x8*)&As[wm0 + i * 16 + l15][quad * 8];
    #pragma unroll
    for (int j = 0; j < NI; ++j)
      bfr[j] = *(const s16x8*)&Bs[wn0 + j * 16 + l15][quad * 8];
    #pragma unroll
    for (int i = 0; i < MI; ++i)
      #pragma unroll
      for (int j = 0; j < NI; ++j)
        acc[i][j] = __builtin_amdgcn_mfma_f32_16x16x32_bf16(af[i], bfr[j], acc[i][j], 0, 0, 0);
  }

  const bool f32m = *fl != 0;
  #pragma unroll
  for (int i = 0; i < MI; ++i) {
    #pragma unroll
    for (int j = 0; j < NI; ++j) {
      const int col = n0 + wn0 + j * 16 + l15;
      const float bvv = bias ? ld(bias, col, f32m) : 0.f;
      #pragma unroll
      for (int v = 0; v < 4; ++v) {
        const int row = m0 + wm0 + i * 16 + quad * 4 + v;
        float val = acc[i][j][v] * alpha + bvv;
        if (GELU) val = 0.5f * val * (1.0f + erff(val * 0.70710678118654752440f));
        if (RESID) val += b2f(resid[(long)row * ldc + col]);
        Cb[(long)row * ldc + col] = f2b(val);
      }
    }
  }
}

// ---------------------------------------------------------------- LayerNorm
// F32OUT: write f32 (final output) vs bf16 (internal).
template<bool F32OUT>
__global__ __launch_bounds__(256)
void ln_kernel(const void* __restrict__ in, const void* __restrict__ g,
               const void* __restrict__ bb, void* __restrict__ out,
               const int* __restrict__ flIn, const int* __restrict__ flGB)
{
  const bool fI = *flIn != 0;
  const bool fG = *flGB != 0;
  const long row = blockIdx.x;
  const long base = row * DIMM;
  const int tid = threadIdx.x;
  __shared__ float s1[8], s2[8];
  float v0 = ld(in, base + tid, fI);
  float v1 = ld(in, base + tid + 256, fI);
  float v2 = ld(in, base + tid + 512, fI);
  float s = v0 + v1 + v2;
  #pragma unroll
  for (int off = 32; off; off >>= 1) s += __shfl_down(s, off);
  const int lane = tid & 63, wid = tid >> 6;
  if (!lane) s1[wid] = s;
  __syncthreads();
  if (!tid) s1[4] = s1[0] + s1[1] + s1[2] + s1[3];
  __syncthreads();
  const float mu = s1[4] / 768.0f;
  float d0 = v0 - mu, d1 = v1 - mu, d2 = v2 - mu;
  float sq = d0 * d0 + d1 * d1 + d2 * d2;
  #pragma unroll
  for (int off = 32; off; off >>= 1) sq += __shfl_down(sq, off);
  if (!lane) s2[wid] = sq;
  __syncthreads();
  if (!tid) s2[4] = s2[0] + s2[1] + s2[2] + s2[3];
  __syncthreads();
  const float var = s2[4] / 768.0f;
  const float rstd = 1.0f / sqrtf(var + 1e-5f);
  float o0 = d0 * rstd * ld(g, tid, fG)       + ld(bb, tid, fG);
  float o1 = d1 * rstd * ld(g, tid + 256, fG) + ld(bb, tid + 256, fG);
  float o2 = d2 * rstd * ld(g, tid + 512, fG) + ld(bb, tid + 512, fG);
  if (F32OUT) {
    float* o = (float*)out + base;
    o[tid] = o0; o[tid + 256] = o1; o[tid + 512] = o2;
  } else {
    u16* o = (u16*)out + base;
    o[tid] = f2b(o0); o[tid + 256] = f2b(o1); o[tid + 512] = f2b(o2);
  }
}

// --------------------------------------- weight transpose: raw -> bf16 out
__global__ __launch_bounds__(256)
void transpose_k(const void* __restrict__ in, u16* __restrict__ out, int R, int C,
                 const int* __restrict__ fl)
{
  const bool f32m = *fl != 0;
  __shared__ u16 t[32][36];
  const int c0 = blockIdx.x * 32;
  const int r0 = blockIdx.y * 32;
  const int tid = threadIdx.x;
  const int i = tid >> 3;
  const int j4 = (tid & 7) * 4;
  #pragma unroll
  for (int jj = 0; jj < 4; ++jj)
    t[i][j4 + jj] = f2b(ld(in, (long)(r0 + i) * C + c0 + j4 + jj, f32m));
  __syncthreads();
  u16x4 ov;
  #pragma unroll
  for (int jj = 0; jj < 4; ++jj) ov[jj] = t[j4 + jj][i];
  *(u16x4*)&out[(long)(c0 + i) * R + r0 + j4] = ov;
}

// ------------------------------------------------- V -> vT[bh][d][n] reshape
__global__ __launch_bounds__(256)
void v_transpose(const u16* __restrict__ v, u16* __restrict__ vT)
{
  __shared__ u16 t[64][72];
  const int z = blockIdx.y;
  const int b = z / HEADS, h = z - b * HEADS;
  const int n0 = blockIdx.x * 64;
  const int tid = threadIdx.x;
  const int i = tid >> 2;
  const int jb = (tid & 3) * 16;
  const u16* src = v + (long)(b * NSEQ + n0 + i) * DIMM + h * DHEAD + jb;
  *(u16x8*)&t[i][jb]     = *(const u16x8*)&src[0];
  *(u16x8*)&t[i][jb + 8] = *(const u16x8*)&src[8];
  __syncthreads();
  const int dd = tid >> 2;
  const int nb = (tid & 3) * 16;
  u16x8 o0, o1;
  #pragma unroll
  for (int nn = 0; nn < 8; ++nn) { o0[nn] = t[nb + nn][dd]; o1[nn] = t[nb + 8 + nn][dd]; }
  u16* dst = vT + ((long)z * DHEAD + dd) * NSEQ + n0 + nb;
  *(u16x8*)&dst[0] = o0;
  *(u16x8*)&dst[8] = o1;
}

// ------------------------------------------------------- epipolar: per-batch
__global__ void epi_setup(const void* __restrict__ intr, const void* __restrict__ c2w,
                          float* __restrict__ u4, float* __restrict__ oijb,
                          const int* __restrict__ fl)
{
  const int db = blockIdx.x;
  const int d = db >> 2, b = db & 3;
  __shared__ float S[36];
  if (threadIdx.x == 0) {
    const bool f32m = *fl != 0;
    const int sidx = (d == 0) ? 1 : 0;
    const int tidx = 1 - sidx;
    float k3[9], sr[9], st[3], tr[9], tt[3];
    const float Wf = 32.0f * 16.0f / 9.0f;
    for (int j = 0; j < 3; ++j) {
      k3[j]     = ld(intr, (b * 4 + 0) * 4 + j, f32m) * Wf;
      k3[3 + j] = ld(intr, (b * 4 + 1) * 4 + j, f32m) * 32.0f;
      k3[6 + j] = ld(intr, (b * 4 + 2) * 4 + j, f32m);
    }
    k3[2] = 16.0f; k3[5] = 16.0f;
    for (int i = 0; i < 3; ++i) {
      for (int j = 0; j < 3; ++j) {
        sr[i * 3 + j] = ld(c2w, ((sidx * 4 + b) * 4 + i) * 4 + j, f32m);
        tr[i * 3 + j] = ld(c2w, ((tidx * 4 + b) * 4 + i) * 4 + j, f32m);
      }
      st[i] = ld(c2w, ((sidx * 4 + b) * 4 + i) * 4 + 3, f32m);
      tt[i] = ld(c2w, ((tidx * 4 + b) * 4 + i) * 4 + 3, f32m);
    }
    double a = tr[0], bb_ = tr[1], c = tr[2];
    double dd2 = tr[3], e = tr[4], f = tr[5];
    double g2 = tr[6], h2 = tr[7], i2 = tr[8];
    double det = a * (e * i2 - f * h2) - bb_ * (dd2 * i2 - f * g2) + c * (dd2 * h2 - e * g2);
    double inv[9] = {
      (e * i2 - f * h2), (c * h2 - bb_ * i2), (bb_ * f - c * e),
      (f * g2 - dd2 * i2), (a * i2 - c * g2), (c * dd2 - a * f),
      (dd2 * h2 - e * g2), (bb_ * g2 - a * h2), (a * e - bb_ * dd2)
    };
    float tri[9];
    for (int t2 = 0; t2 < 9; ++t2) tri[t2] = (float)(inv[t2] / det);
    float o2[3], oij[3];
    for (int i3 = 0; i3 < 3; ++i3)
      o2[i3] = tri[i3 * 3] * st[0] + tri[i3 * 3 + 1] * st[1] + tri[i3 * 3 + 2] * st[2] - tt[i3];
    for (int i3 = 0; i3 < 3; ++i3)
      oij[i3] = k3[i3 * 3] * o2[0] + k3[i3 * 3 + 1] * o2[1] + k3[i3 * 3 + 2] * o2[2];
    const float ozf = oij[2];
    oij[0] = oij[0] / ozf; oij[1] = oij[1] / ozf; oij[2] = ozf / ozf;
    for (int t2 = 0; t2 < 9; ++t2) { S[t2] = k3[t2]; S[9 + t2] = sr[t2]; S[21 + t2] = tri[t2]; }
    for (int t2 = 0; t2 < 3; ++t2) { S[18 + t2] = st[t2]; S[30 + t2] = tt[t2]; S[33 + t2] = oij[t2]; }
    oijb[db * 4 + 0] = oij[0]; oijb[db * 4 + 1] = oij[1]; oijb[db * 4 + 2] = oij[2];
    oijb[db * 4 + 3] = 0.f;
  }
  __syncthreads();
  for (int n = threadIdx.x; n < 1024; n += blockDim.x) {
    const float ncx = ((float)(n & 31) - S[2]) / S[0];
    const float ncy = ((float)(n >> 5) - S[5]) / S[4];
    const float p0 = S[9]  * ncx + S[10] * ncy + S[11] + S[18];
    const float p1 = S[12] * ncx + S[13] * ncy + S[14] + S[19];
    const float p2 = S[15] * ncx + S[16] * ncy + S[17] + S[20];
    const float q0 = S[21] * p0 + S[22] * p1 + S[23] * p2 - S[30];
    const float q1 = S[24] * p0 + S[25] * p1 + S[26] * p2 - S[31];
    const float q2 = S[27] * p0 + S[28] * p1 + S[29] * p2 - S[32];
    const float w0 = S[0] * q0 + S[1] * q1 + S[2] * q2;
    const float w1 = S[3] * q0 + S[4] * q1 + S[5] * q2;
    const float w2 = S[6] * q0 + S[7] * q1 + S[8] * q2;
    const float pz = w2 + 1e-6f;
    const float ux = w0 / pz - S[33];
    const float uy = w1 / pz - S[34];
    const float uz = w2 / pz - S[35];
    const float vlen = sqrtf(ux * ux + uy * uy + uz * uz);
    f32x4 uo = {ux, uy, uz, vlen};
    *(f32x4*)&u4[((long)db * 1024 + n) * 4] = uo;
  }
}

// -------------------------------------------- epipolar: dw rows (+row where)
__global__ __launch_bounds__(256)
void epi_dw(const float* __restrict__ u4, const float* __restrict__ oijb,
            float* __restrict__ dw)
{
  const int rowid = blockIdx.x;
  const int db = rowid >> 10;
  const f32x4 U = *(const f32x4*)&u4[(long)rowid * 4];
  const float ox = oijb[db * 4 + 0];
  const float oy = oijb[db * 4 + 1];
  const float oz = oijb[db * 4 + 2];
  const int tid = threadIdx.x;
  __shared__ float red[8];
  float vals[4];
  float mx = -1e30f;
  #pragma unroll
  for (int i = 0; i < 4; ++i) {
    const int m = tid + i * 256;
    const float cx = (float)(m & 31) - ox;
    const float cy = (float)(m >> 5) - oy;
    const float cz = 1.0f - oz;
    const float crx = U.y * cz - U.z * cy;
    const float cry = U.z * cx - U.x * cz;
    const float crz = U.x * cy - U.y * cx;
    const float area = sqrtf(crx * crx + cry * cry + crz * crz);
    const float dist = area / U.w;
    const float t = 50.0f * (dist - 0.5f);
    const float dwv = 1.0f - 1.0f / (1.0f + expf(-t));
    vals[i] = dwv;
    mx = fmaxf(mx, dwv);
  }
  #pragma unroll
  for (int off = 32; off; off >>= 1) mx = fmaxf(mx, __shfl_down(mx, off));
  const int lane = tid & 63, wid = tid >> 6;
  if (!lane) red[wid] = mx;
  __syncthreads();
  if (!tid) red[4] = fmaxf(fmaxf(red[0], red[1]), fmaxf(red[2], red[3]));
  __syncthreads();
  const bool fill1 = red[4] < 0.5f;
  float* out = dw + (long)rowid * 1024;
  #pragma unroll
  for (int i = 0; i < 4; ++i)
    out[tid + i * 256] = fill1 ? 1.0f : vals[i];
}

// ------------------- wmap(bf16)[b][q][k] = bf16(e1[q][k]*e2raw[k][q])
__global__ __launch_bounds__(256)
void epi_wmap(const float* __restrict__ dw, u16* __restrict__ wm)
{
  __shared__ float tb[32][33];
  const int b = blockIdx.z;
  const int q0 = blockIdx.x * 32;
  const int k0 = blockIdx.y * 32;
  const int tid = threadIdx.x;
  const int i = tid >> 3;
  const int j4 = (tid & 7) * 4;
  const float* d1 = dw + ((long)(4 + b) * 1024 + (k0 + i)) * 1024 + q0 + j4;
  #pragma unroll
  for (int jj = 0; jj < 4; ++jj) tb[i][j4 + jj] = d1[jj];
  __syncthreads();
  const float* d0 = dw + ((long)b * 1024 + (q0 + i)) * 1024 + k0 + j4;
  u16x4 pk;
  #pragma unroll
  for (int jj = 0; jj < 4; ++jj) pk[jj] = f2b(d0[jj] * tb[j4 + jj][i]);
  *(u16x4*)&wm[((long)b * 1024 + q0 + i) * 1024 + k0 + j4] = pk;
}

// ------------------------------- wm_full f32 broadcast (last kernel of all)
__global__ __launch_bounds__(256)
void wm_write(const u16* __restrict__ wm, float* __restrict__ out)
{
  const int q = blockIdx.x;
  const int z = blockIdx.y;
  const int b = z / HEADS;
  u16x4 w = *(const u16x4*)&wm[((long)b * 1024 + q) * 1024 + threadIdx.x * 4];
  f32x4 o;
  #pragma unroll
  for (int jj = 0; jj < 4; ++jj) o[jj] = b2f(w[jj]);
  *(f32x4*)&out[((long)z * 1024 + q) * 1024 + threadIdx.x * 4] = o;
}

// ------------------------------------------- softmax((scale*qk)*w) in-place
__global__ __launch_bounds__(256)
void softmax_kernel(u16* __restrict__ att, const u16* __restrict__ wm)
{
  const int q = blockIdx.x;
  const int z = blockIdx.y;
  const int b = z / HEADS;
  u16* row = att + ((long)z * NSEQ + q) * NSEQ;
  const u16* wr = wm + ((long)b * NSEQ + q) * NSEQ;
  const int tid = threadIdx.x;
  __shared__ float r1[8], r2[8];
  u16x4 sv = *(const u16x4*)&row[tid * 4];
  u16x4 wv = *(const u16x4*)&wr[tid * 4];
  float p[4];
  float mx = -1e30f;
  #pragma unroll
  for (int jj = 0; jj < 4; ++jj) { p[jj] = b2f(sv[jj]) * b2f(wv[jj]); mx = fmaxf(mx, p[jj]); }
  #pragma unroll
  for (int off = 32; off; off >>= 1) mx = fmaxf(mx, __shfl_down(mx, off));
  const int lane = tid & 63, wid = tid >> 6;
  if (!lane) r1[wid] = mx;
  __syncthreads();
  if (!tid) r1[4] = fmaxf(fmaxf(r1[0], r1[1]), fmaxf(r1[2], r1[3]));
  __syncthreads();
  const float m = r1[4];
  float e[4]; float s = 0.f;
  #pragma unroll
  for (int jj = 0; jj < 4; ++jj) { e[jj] = expf(p[jj] - m); s += e[jj]; }
  #pragma unroll
  for (int off = 32; off; off >>= 1) s += __shfl_down(s, off);
  if (!lane) r2[wid] = s;
  __syncthreads();
  if (!tid) r2[4] = r2[0] + r2[1] + r2[2] + r2[3];
  __syncthreads();
  const float inv = 1.0f / r2[4];
  u16x4 ov;
  #pragma unroll
  for (int jj = 0; jj < 4; ++jj) ov[jj] = f2b(e[jj] * inv);
  *(u16x4*)&row[tid * 4] = ov;
}

// ---------------------------------------------------------------------------
extern "C" void kernel_launch(void* const* d_in, const int* in_sizes, int n_in,
                              void* d_out, int out_size, void* d_ws, size_t ws_size,
                              hipStream_t stream)
{
  (void)in_sizes; (void)n_in; (void)out_size; (void)ws_size;
  const void* x     = d_in[0];
  const void* src   = d_in[1];
  const void* intr  = d_in[2];
  const void* c2w   = d_in[3];
  const void* lnq_g = d_in[4];
  const void* lnq_b = d_in[5];
  const void* Wq    = d_in[6];
  const void* bq    = d_in[7];
  const void* lnk_g = d_in[8];
  const void* lnk_b = d_in[9];
  const void* Wk    = d_in[10];
  const void* bk    = d_in[11];
  const void* lnv_g = d_in[12];
  const void* lnv_b = d_in[13];
  const void* Wv    = d_in[14];
  const void* bv    = d_in[15];
  const void* Wp    = d_in[16];
  const void* bp    = d_in[17];
  const void* pre_g = d_in[18];
  const void* pre_b = d_in[19];
  const void* W1    = d_in[20];
  const void* b1    = d_in[21];
  const void* W2    = d_in[22];
  const void* b2    = d_in[23];
  const void* post_g= d_in[24];
  const void* post_b= d_in[25];

  char* ws = (char*)d_ws;
  size_t off = 0;
  auto alloc = [&](size_t bytes) -> char* {
    char* p = ws + off;
    off = (off + bytes + 255) & ~(size_t)255;
    return p;
  };
  const size_t SEQD = (size_t)4096 * 768 * 2;   // 6.29 MB slot

  int* dflag = (int*)alloc(256);
  int* zflag = dflag + 1;
  u16* WqT = (u16*)alloc(768 * 768 * 2);
  u16* WkT = (u16*)alloc(768 * 768 * 2);
  u16* WvT = (u16*)alloc(768 * 768 * 2);
  u16* WpT = (u16*)alloc(768 * 768 * 2);
  u16* W1T = (u16*)alloc(768 * 1536 * 2);
  u16* W2T = (u16*)alloc(1536 * 768 * 2);
  char* pool = alloc(5 * SEQD);                            // 31.5 MB, 5 slots
  float* u4   = (float*)alloc(8 * 1024 * 4 * 4);
  float* oijb = (float*)alloc(8 * 4 * 4);
  u16* wmapb  = (u16*)alloc((size_t)4 * 1024 * 1024 * 2);  // bf16 wmap, 8.4 MB
  // total ws ~= 49.4 MB

  u16* S0 = (u16*)pool;                 // LN scratch -> zbuf
  u16* S1 = (u16*)(pool + SEQD);        // qb -> abuf -> t1
  u16* S2 = (u16*)(pool + 2 * SEQD);    // kb -> t0
  u16* S3 = (u16*)(pool + 3 * SEQD);    // vb -> hbuf (S3+S4)
  u16* S4 = (u16*)(pool + 4 * SEQD);    // vT -> hbuf upper half

  // ---- outputs are FLOAT32 (reference returns f32) ----
  float* out_z  = (float*)d_out;                              // 3.1M f32
  float* out_wm = (float*)d_out + (size_t)4 * 1024 * 768;     // 50.3M f32 (201 MB)
  // scratch overlays inside d_out (all dead before their regions are written):
  u16* scores  = (u16*)out_wm;        // bf16 scores: 100.7 MB inside the wm region
  float* dwbuf = (float*)d_out;       // 33.6 MB at front; dead before scores GEMM

  detect_dtype<<<1, 64, 0, stream>>>((const unsigned*)lnq_g, dflag);

  // weight transposes (all GEMMs become BT flavor)
  transpose_k<<<dim3(24, 24), 256, 0, stream>>>(Wq, WqT, 768, 768, dflag);
  transpose_k<<<dim3(24, 24), 256, 0, stream>>>(Wk, WkT, 768, 768, dflag);
  transpose_k<<<dim3(24, 24), 256, 0, stream>>>(Wv, WvT, 768, 768, dflag);
  transpose_k<<<dim3(24, 24), 256, 0, stream>>>(Wp, WpT, 768, 768, dflag);
  transpose_k<<<dim3(48, 24), 256, 0, stream>>>(W1, W1T, 768, 1536, dflag);
  transpose_k<<<dim3(24, 48), 256, 0, stream>>>(W2, W2T, 1536, 768, dflag);

  // epipolar weights (dw staged in d_out front, consumed before scores GEMM)
  epi_setup<<<8, 128, 0, stream>>>(intr, c2w, u4, oijb, dflag);
  epi_dw<<<8192, 256, 0, stream>>>(u4, oijb, dwbuf);
  epi_wmap<<<dim3(32, 32, 4), 256, 0, stream>>>(dwbuf, wmapb);

  // Q path
  ln_kernel<false><<<4096, 256, 0, stream>>>(x, lnq_g, lnq_b, S0, dflag, dflag);
  gemm_bt<128,128,false,false><<<dim3(32, 6, 1), 256, 0, stream>>>(
      S0, WqT, bq, nullptr, S1, dflag, 768, 768, 768, 768, 0,0,0,0,0,0, 1.0f);
  // K path
  ln_kernel<false><<<4096, 256, 0, stream>>>(src, lnk_g, lnk_b, S0, dflag, dflag);
  gemm_bt<128,128,false,false><<<dim3(32, 6, 1), 256, 0, stream>>>(
      S0, WkT, bk, nullptr, S2, dflag, 768, 768, 768, 768, 0,0,0,0,0,0, 1.0f);
  // V path
  ln_kernel<false><<<4096, 256, 0, stream>>>(src, lnv_g, lnv_b, S0, dflag, dflag);
  gemm_bt<128,128,false,false><<<dim3(32, 6, 1), 256, 0, stream>>>(
      S0, WvT, bv, nullptr, S3, dflag, 768, 768, 768, 768, 0,0,0,0,0,0, 1.0f);
  v_transpose<<<dim3(16, 48), 256, 0, stream>>>(S3, S4);

  // scores = 0.125 * q k^T  (bf16, overlaid in the wm region)
  gemm_bt<128,128,false,false><<<dim3(8, 8, 48), 256, 0, stream>>>(
      S1, S2, nullptr, nullptr, scores, dflag,
      64, 768, 768, 1024,
      (long)1024*768, 64, (long)1024*768, 64,
      (long)12*1024*1024, (long)1024*1024, 0.125f);

  // softmax(scores * wmap) in-place
  softmax_kernel<<<dim3(1024, 48), 256, 0, stream>>>(scores, wmapb);

  // a = att @ v  -> abuf (S1; qb dead)
  gemm_bt<128,64,false,false><<<dim3(8, 1, 48), 256, 0, stream>>>(
      scores, S4, nullptr, nullptr, S1, dflag,
      1024, 1024, 1024, 768,
      (long)12*1024*1024, (long)1024*1024,
      (long)12*64*1024, (long)64*1024,
      (long)1024*768, 64, 1.0f);

  // proj: t0 (S2) = a @ Wp + bp
  gemm_bt<128,128,false,false><<<dim3(32, 6, 1), 256, 0, stream>>>(
      S1, WpT, bp, nullptr, S2, dflag, 768, 768, 768, 768, 0,0,0,0,0,0, 1.0f);

  // zbuf (S0) = LN(t0)
  ln_kernel<false><<<4096, 256, 0, stream>>>(S2, pre_g, pre_b, S0, zflag, dflag);

  // h (S3..S4) = gelu(z @ W1 + b1)
  gemm_bt<128,128,true,false><<<dim3(32, 12, 1), 256, 0, stream>>>(
      S0, W1T, b1, nullptr, S3, dflag, 768, 768, 768, 1536, 0,0,0,0,0,0, 1.0f);

  // t1 (S1) = z + (h @ W2 + b2)
  gemm_bt<128,128,false,true><<<dim3(32, 6, 1), 256, 0, stream>>>(
      S3, W2T, b2, S0, S1, dflag, 1536, 1536, 1536, 768, 0,0,0,0,0,0, 1.0f);

  // out_z = LN(t1)  — f32 output
  ln_kernel<true><<<4096, 256, 0, stream>>>(S1, post_g, post_b, out_z, zflag, dflag);

  // wm_full f32 (scores scratch now dead)
  wm_write<<<dim3(1024, 48), 256, 0, stream>>>(wmapb, out_wm);
}